// Round 15
// baseline (1210.166 us; speedup 1.0000x reference)
//
#include <hip/hip_runtime.h>

#define LB __launch_bounds__(256)

constexpr int S = 19;

typedef __attribute__((ext_vector_type(8))) short frag16;   // 8 bf16 (4 VGPR)
typedef __attribute__((ext_vector_type(8))) ushort ushort8;
typedef __attribute__((ext_vector_type(4))) float f32x4;

__device__ __forceinline__ int reflect256(int i) { return i < 0 ? -i : (i > 255 ? 510 - i : i); }
__device__ __forceinline__ int reflect128(int i) { return i < 0 ? -i : (i > 127 ? 254 - i : i); }

__device__ __forceinline__ ushort f2bf(float f) {
    union { float f; uint u; } a; a.f = f;
    uint r = a.u + 0x7fffu + ((a.u >> 16) & 1u);   // round-nearest-even
    return (ushort)(r >> 16);
}
__device__ __forceinline__ float bf2f(ushort u) {
    union { uint u; float f; } a; a.u = ((uint)u) << 16; return a.f;
}

// async global->LDS, 16B per lane; LDS dest = wave-uniform base + lane*16 (linear)
__device__ __forceinline__ void gll16(const void* g, void* l) {
    __builtin_amdgcn_global_load_lds(
        (const __attribute__((address_space(1))) void*)g,
        (__attribute__((address_space(3))) void*)l, 16, 0, 0);
}

// ---------------- prep: weight transposes + zero accumulator region ----------------
__global__ LB void k_prep(const float* __restrict__ w2, const float* __restrict__ w3,
                          const float* __restrict__ w4, const float* __restrict__ w5,
                          ushort* __restrict__ t2, ushort* __restrict__ t3,
                          ushort* __restrict__ t4, ushort* __restrict__ t5,
                          float* __restrict__ zf, int ZN) {
    int e = blockIdx.x * 256 + threadIdx.x;    // 1,566,720 total
    if (e < ZN) zf[e] = 0.f;
    if (e < 18432) {
        int ci = e & 31, co = (e >> 5) & 63, tap = e >> 11;
        t2[e] = f2bf(w2[(co * 32 + ci) * 9 + tap]);
    } else if (e < 18432 + 73728) {
        int e2 = e - 18432;
        int ci = e2 & 63, co = (e2 >> 6) & 127, tap = e2 >> 13;
        t3[e2] = f2bf(w3[(co * 64 + ci) * 9 + tap]);
    } else if (e < 18432 + 73728 + 294912) {
        int e3 = e - (18432 + 73728);
        int ci = e3 & 127, co = (e3 >> 7) & 255, tap = e3 >> 15;
        t4[e3] = f2bf(w4[ci * 2304 + co * 9 + tap]);   // w4 is (Cin,Cout,kh,kw)
    } else {
        int e4 = e - (18432 + 73728 + 294912);
        int ci = e4 & 255, co = (e4 >> 8) & 511, tap = e4 >> 17;
        t5[e4] = f2bf(w5[(co * 256 + ci) * 9 + tap]);
    }
}

// ---------------- conv1 (+ fused label map): [8,3,256,256] f32 -> [8,256,256,32] bf16 CL ----
// blocks 0..511 additionally compute the 128x128 nearest-resize label map + class counts
// (counts was zeroed by k_prep, which precedes this kernel in stream order).
__global__ LB void k_conv1cl(const float* __restrict__ in, const float* __restrict__ w,
                             const float* __restrict__ bias, ushort* __restrict__ out,
                             const float* __restrict__ segmap, int* __restrict__ lab,
                             int* __restrict__ counts) {
    __shared__ float Wr[864];   // [co][ci*9+tap]
    __shared__ float Bs[32];
    __shared__ int h[S];
    int t = threadIdx.x;
    int bx = blockIdx.x;
    for (int e = t; e < 864; e += 256) Wr[e] = w[e];
    if (t < 32) Bs[t] = bias[t];
    if (t < S) h[t] = 0;
    __syncthreads();
    int idx = bx * 256 + t;          // 524288 pixels
    int x = idx & 255, y = (idx >> 8) & 255, b = idx >> 16;
    float v[27];
    #pragma unroll
    for (int ci = 0; ci < 3; ++ci) {
        const float* ip = in + ((b * 3 + ci) << 16);
        #pragma unroll
        for (int ky = 0; ky < 3; ++ky) {
            int iy = reflect256(y + ky - 1);
            #pragma unroll
            for (int kx = 0; kx < 3; ++kx) {
                int ix = reflect256(x + kx - 1);
                v[ci * 9 + ky * 3 + kx] = ip[(iy << 8) + ix];
            }
        }
    }
    ushort* op = out + (long)idx * 32;
    #pragma unroll
    for (int g = 0; g < 4; ++g) {
        ushort8 o;
        #pragma unroll
        for (int j = 0; j < 8; ++j) {
            int co = g * 8 + j;
            float a = Bs[co];
            #pragma unroll
            for (int k = 0; k < 27; ++k) a += v[k] * Wr[co * 27 + k];
            o[j] = f2bf(a);
        }
        *(ushort8*)(op + g * 8) = o;
    }
    // ---- fused label map (blocks 0..511 cover 8*128*128 sites) ----
    if (bx < 512) {
        int i2 = bx * 256 + t;
        int lx = i2 & 127, ly = (i2 >> 7) & 127, lb = i2 >> 14;
        const float* sp = segmap + (long)lb * S * 65536 + (ly << 1) * 256 + (lx << 1);
        int s = 0;
        for (int c = 0; c < S; ++c) {
            if (sp[c * 65536] > 0.f) { s = c; break; }
        }
        lab[i2] = s;
        atomicAdd(&h[s], 1);
        __syncthreads();
        if (t < S) atomicAdd(&counts[lb * S + t], h[t]);
    }
}

// ---------------- channels-last instance-norm: block partials -> global atomic accum ----
template <int C, int PB, int SPLITS>
__global__ LB void k_stats_cl(const ushort* __restrict__ x,
                              float* __restrict__ psum, float* __restrict__ pss) {
    __shared__ float lsum[C], lss[C];
    int b = blockIdx.x / SPLITS, sp = blockIdx.x % SPLITS;
    int t = threadIdx.x;
    if (t < C) { lsum[t] = 0.f; lss[t] = 0.f; }
    __syncthreads();
    constexpr int CG = C / 8;
    constexpr int PO = 256 / CG;
    int c0 = (t % CG) * 8;
    int po = t / CG;
    float s[8], ss[8];
    #pragma unroll
    for (int k = 0; k < 8; ++k) { s[k] = 0.f; ss[k] = 0.f; }
    const ushort* base = x + ((long)b * SPLITS + sp) * (long)PB * C;
    for (int p = po; p < PB; p += PO) {
        ushort8 v = *(const ushort8*)(base + (long)p * C + c0);
        #pragma unroll
        for (int k = 0; k < 8; ++k) {
            float f = bf2f(v[k]);
            s[k] += f; ss[k] += f * f;
        }
    }
    #pragma unroll
    for (int k = 0; k < 8; ++k) {
        atomicAdd(&lsum[c0 + k], s[k]);
        atomicAdd(&lss[c0 + k], ss[k]);
    }
    __syncthreads();
    if (t < C) {
        atomicAdd(&psum[b * C + t], lsum[t]);
        atomicAdd(&pss[b * C + t], lss[t]);
    }
}

// ---------------- normalize + leaky-relu in place; mean/istd computed in-block ----------
template <int C, int P>
__global__ LB void k_nl_cl(ushort* __restrict__ x, const float* __restrict__ psum,
                           const float* __restrict__ pss) {
    __shared__ float M[C], I[C];
    int t = threadIdx.x;
    long e0 = (long)blockIdx.x * 2048;         // elements per block
    int b = (int)(e0 / ((long)P * C));
    if (t < C) {
        float s = psum[b * C + t], q = pss[b * C + t];
        float m = s / (float)P;
        float v = q / (float)P - m * m;
        M[t] = m;
        I[t] = rsqrtf(v + 1e-5f);
    }
    __syncthreads();
    long e = e0 + t * 8;
    int c0 = (int)(e % C);
    ushort8 v = *(ushort8*)(x + e);
    #pragma unroll
    for (int k = 0; k < 8; ++k) {
        float u = (bf2f(v[k]) - M[c0 + k]) * I[c0 + k];
        u = u > 0.f ? u : 0.2f * u;
        v[k] = f2bf(u);
    }
    *(ushort8*)(x + e) = v;
}

// ---------------- conv2 MFMA: [8,256,256,32] -> [8,128,128,64], s2 p1 zero-pad ----------------
__global__ LB void k_conv2m(const ushort* __restrict__ xin, const ushort* __restrict__ wt,
                            const float* __restrict__ bias, ushort* __restrict__ xout) {
    int bx = blockIdx.x;
    int y = bx & 127, b = bx >> 7;
    int t = threadIdx.x, w = t >> 6, lane = t & 63;
    int col0 = w * 32;
    int lanep = lane & 15, hi = lane >> 4;

    f32x4 acc[4][2];
    #pragma unroll
    for (int m = 0; m < 4; ++m)
        #pragma unroll
        for (int n = 0; n < 2; ++n) acc[m][n] = (f32x4){0.f, 0.f, 0.f, 0.f};

    #pragma unroll
    for (int ky = 0; ky < 3; ++ky) {
        int iy = 2 * y + ky - 1;
        if (iy < 0) continue;
        #pragma unroll
        for (int kx = 0; kx < 3; ++kx) {
            int tap = ky * 3 + kx;
            const ushort* wb = wt + ((tap * 64 + lanep) << 5) + hi * 8;
            frag16 av[4];
            #pragma unroll
            for (int m = 0; m < 4; ++m) av[m] = *(const frag16*)(wb + ((m * 16) << 5));
            frag16 bv[2];
            #pragma unroll
            for (int n = 0; n < 2; ++n) {
                int xo = col0 + n * 16 + lanep;
                int ix = 2 * xo + kx - 1;
                frag16 vv = (frag16)(short)0;
                if (ix >= 0)
                    vv = *(const frag16*)(xin + ((((long)(b * 256 + iy)) << 8) + ix) * 32 + hi * 8);
                bv[n] = vv;
            }
            #pragma unroll
            for (int m = 0; m < 4; ++m)
                #pragma unroll
                for (int n = 0; n < 2; ++n)
                    acc[m][n] = __builtin_amdgcn_mfma_f32_16x16x32_bf16(av[m], bv[n], acc[m][n], 0, 0, 0);
        }
    }
    float bvv[4][4];
    #pragma unroll
    for (int m = 0; m < 4; ++m)
        #pragma unroll
        for (int r = 0; r < 4; ++r) bvv[m][r] = bias[m * 16 + hi * 4 + r];
    #pragma unroll
    for (int n = 0; n < 2; ++n) {
        int xo = col0 + n * 16 + lanep;
        long pb = ((((long)(b * 128 + y)) << 7) + xo) * 64 + hi * 4;
        #pragma unroll
        for (int m = 0; m < 4; ++m) {
            ushort4 o;
            o.x = f2bf(acc[m][n][0] + bvv[m][0]);
            o.y = f2bf(acc[m][n][1] + bvv[m][1]);
            o.z = f2bf(acc[m][n][2] + bvv[m][2]);
            o.w = f2bf(acc[m][n][3] + bvv[m][3]);
            *(ushort4*)(xout + pb + m * 16) = o;
        }
    }
}

// ---------------- conv3 MFMA: [8,128,128,64] -> [8,64,64,128], s2 p1 zero-pad ----------------
__global__ LB void k_conv3m(const ushort* __restrict__ xin, const ushort* __restrict__ wt,
                            const float* __restrict__ bias, ushort* __restrict__ xout) {
    int bx = blockIdx.x;
    int y = bx & 63, b = bx >> 6;
    int t = threadIdx.x, w = t >> 6, lane = t & 63;
    int co0 = (w >> 1) * 64;
    int col0 = (w & 1) * 32;
    int lanep = lane & 15, hi = lane >> 4;

    f32x4 acc[4][2];
    #pragma unroll
    for (int m = 0; m < 4; ++m)
        #pragma unroll
        for (int n = 0; n < 2; ++n) acc[m][n] = (f32x4){0.f, 0.f, 0.f, 0.f};

    #pragma unroll
    for (int ky = 0; ky < 3; ++ky) {
        int iy = 2 * y + ky - 1;
        if (iy < 0) continue;
        #pragma unroll
        for (int kx = 0; kx < 3; ++kx) {
            int tap = ky * 3 + kx;
            #pragma unroll
            for (int ck = 0; ck < 2; ++ck) {
                int ci0 = ck * 32;
                const ushort* wb = wt + ((tap * 128 + co0 + lanep) << 6) + ci0 + hi * 8;
                frag16 av[4];
                #pragma unroll
                for (int m = 0; m < 4; ++m) av[m] = *(const frag16*)(wb + ((m * 16) << 6));
                frag16 bv[2];
                #pragma unroll
                for (int n = 0; n < 2; ++n) {
                    int xo = col0 + n * 16 + lanep;
                    int ix = 2 * xo + kx - 1;
                    frag16 vv = (frag16)(short)0;
                    if (ix >= 0)
                        vv = *(const frag16*)(xin + ((((long)(b * 128 + iy)) << 7) + ix) * 64 + ci0 + hi * 8);
                    bv[n] = vv;
                }
                #pragma unroll
                for (int m = 0; m < 4; ++m)
                    #pragma unroll
                    for (int n = 0; n < 2; ++n)
                        acc[m][n] = __builtin_amdgcn_mfma_f32_16x16x32_bf16(av[m], bv[n], acc[m][n], 0, 0, 0);
            }
        }
    }
    float bvv[4][4];
    #pragma unroll
    for (int m = 0; m < 4; ++m)
        #pragma unroll
        for (int r = 0; r < 4; ++r) bvv[m][r] = bias[co0 + m * 16 + hi * 4 + r];
    #pragma unroll
    for (int n = 0; n < 2; ++n) {
        int xo = col0 + n * 16 + lanep;
        long pb = ((((long)(b * 64 + y)) << 6) + xo) * 128 + co0 + hi * 4;
        #pragma unroll
        for (int m = 0; m < 4; ++m) {
            ushort4 o;
            o.x = f2bf(acc[m][n][0] + bvv[m][0]);
            o.y = f2bf(acc[m][n][1] + bvv[m][1]);
            o.z = f2bf(acc[m][n][2] + bvv[m][2]);
            o.w = f2bf(acc[m][n][3] + bvv[m][3]);
            *(ushort4*)(xout + pb + m * 16) = o;
        }
    }
}

// ---------------- convT4 MFMA (parity decomposition): [8,64,64,128] -> [8,128,128,256] ----
__global__ LB void k_convt4m(const ushort* __restrict__ x3l, const ushort* __restrict__ wt,
                             const float* __restrict__ bias, ushort* __restrict__ xl) {
    int bx = blockIdx.x;
    int parity = bx & 3;
    int py = parity >> 1, px = parity & 1;
    int rg = (bx >> 2) & 15;
    int ct = (bx >> 6) & 3;
    int b  = bx >> 8;
    int co0 = ct * 64;
    int t = threadIdx.x;
    int w = t >> 6;
    int ip = rg * 4 + w;
    int lane = t & 63;
    int lanep = lane & 15;
    int hi = lane >> 4;
    int laneq = hi * 8;

    f32x4 acc[4][4];
    #pragma unroll
    for (int m = 0; m < 4; ++m)
        #pragma unroll
        for (int n = 0; n < 4; ++n) acc[m][n] = (f32x4){0.f, 0.f, 0.f, 0.f};

    #pragma unroll
    for (int ky = 0; ky < 3; ++ky) {
        if (((ky + py) & 1) == 0) continue;
        int i = ip + ((py == 1 && ky == 0) ? 1 : 0);
        if (i >= 64) continue;
        #pragma unroll
        for (int kx = 0; kx < 3; ++kx) {
            if (((kx + px) & 1) == 0) continue;
            int dxp = (px == 1 && kx == 0) ? 1 : 0;
            int tap = ky * 3 + kx;
            const ushort* wbase = wt + (((long)tap * 256 + co0 + lanep) << 7) + laneq;
            const ushort* xbase = x3l + ((((long)b << 12) + (i << 6)) << 7) + laneq;
            #pragma unroll
            for (int ci0 = 0; ci0 < 128; ci0 += 32) {
                frag16 av[4], bv[4];
                #pragma unroll
                for (int m = 0; m < 4; ++m)
                    av[m] = *(const frag16*)(wbase + ((m * 16) << 7) + ci0);
                #pragma unroll
                for (int n = 0; n < 4; ++n) {
                    int j = n * 16 + lanep + dxp;
                    bool valid = j < 64;
                    frag16 v = *(const frag16*)(xbase + ((valid ? j : 63) << 7) + ci0);
                    if (!valid) v = (frag16)(short)0;
                    bv[n] = v;
                }
                #pragma unroll
                for (int m = 0; m < 4; ++m)
                    #pragma unroll
                    for (int n = 0; n < 4; ++n)
                        acc[m][n] = __builtin_amdgcn_mfma_f32_16x16x32_bf16(av[m], bv[n], acc[m][n], 0, 0, 0);
            }
        }
    }

    float bvv[4][4];
    #pragma unroll
    for (int m = 0; m < 4; ++m)
        #pragma unroll
        for (int r = 0; r < 4; ++r)
            bvv[m][r] = bias[co0 + m * 16 + hi * 4 + r];
    int y = 2 * ip + py;
    #pragma unroll
    for (int n = 0; n < 4; ++n) {
        int x = 2 * (n * 16 + lanep) + px;
        long pb = ((((long)b << 14) + (y << 7) + x) << 8) + co0 + hi * 4;
        #pragma unroll
        for (int m = 0; m < 4; ++m) {
            ushort4 o;
            o.x = f2bf(acc[m][n][0] + bvv[m][0]);
            o.y = f2bf(acc[m][n][1] + bvv[m][1]);
            o.z = f2bf(acc[m][n][2] + bvv[m][2]);
            o.w = f2bf(acc[m][n][3] + bvv[m][3]);
            *(ushort4*)(xl + pb + m * 16) = o;
        }
    }
}

// ---------------- conv5 MFMA implicit GEMM v11: X via gll16 single-buffer, W in registers ----
// xl: [8][128][128][256] bf16; wt: [9][512][256] bf16
// block (256 thr, 4 waves): b, co-tile 64 (ct 0..7), row-pair (yp 0..63).
// LDS: X only (33,280B) + part alias. Per chunk: issue 8 X glls + load 36 W frags to regs
// (statically indexed, rule #20); barrier drains both; compute reads A from regs, B from LDS.
// VGPR ~ 144(W) + 64(acc) + ~35 misc <= 256 cap at (256,2) -> no spill, 2 blocks/CU.
__global__ void __launch_bounds__(256, 2)
k_conv5m(const ushort* __restrict__ xl, const ushort* __restrict__ wt,
         const float* __restrict__ bias, const int* __restrict__ lab,
         float* __restrict__ sumbuf) {
    __shared__ __align__(16) ushort L[16640];
    float* part = (float*)L;                 // aliased in epilogue (4,864 B)

    int bx = blockIdx.x;
    int yp = bx & 63;
    int ct = (bx >> 6) & 7;
    int b  = bx >> 9;
    int y0 = yp * 2, cob = ct * 64;
    int t = threadIdx.x;
    int w = t >> 6;
    int lane = t & 63;
    int row_w = w & 1;
    int col0 = (w >> 1) * 64;
    int lanep = lane & 15;
    int hi = lane >> 4;
    int laneq = hi * 8;

    // ---- X staging offsets (swizzled global source, linear LDS dest; rule #21) ----
    long xbase = (long)b << 14;
    int xg[9];
    #pragma unroll
    for (int k = 0; k < 9; ++k) {
        int e = t + k * 256;
        int q = e & 3, p = e >> 2;
        int qp = q ^ ((p >> 1) & 3);
        if (e < 2080) {
            int r = p / 130, c = p - r * 130;
            int gy = reflect128(y0 - 1 + r);
            int gc = reflect128(c - 1);
            xg[k] = (int)(((xbase + (gy << 7) + gc) << 8) + qp * 8);
        } else xg[k] = (int)(xbase << 8);       // never issued
    }
    // ---- W per-lane fragment addresses (A-frag layout): + tap*131072 + ci0 at use ----
    int wbo[4];
    #pragma unroll
    for (int m = 0; m < 4; ++m)
        wbo[m] = ((cob + m * 16 + lanep) << 8) + laneq;

    f32x4 acc[4][4];
    #pragma unroll
    for (int m = 0; m < 4; ++m)
        #pragma unroll
        for (int n = 0; n < 4; ++n) acc[m][n] = (f32x4){0.f, 0.f, 0.f, 0.f};

    frag16 wr_[9][4];

    #pragma unroll 1
    for (int c8 = 0; c8 < 8; ++c8) {
        int cin = c8 * 32;
        // ---- stage X chunk (async to LDS) + W chunk (to registers) ----
        #pragma unroll
        for (int k = 0; k < 8; ++k) gll16(xl + xg[k] + cin, L + ((k << 8) + t) * 8);
        if (t < 32) gll16(xl + xg[8] + cin, L + ((8 << 8) + t) * 8);
        #pragma unroll
        for (int tap = 0; tap < 9; ++tap)
            #pragma unroll
            for (int m = 0; m < 4; ++m)
                wr_[tap][m] = *(const frag16*)(wt + tap * 131072 + wbo[m] + cin);
        __syncthreads();   // drains vmcnt(0): X in LDS, W in regs
        // ---- compute 9 taps: A from regs, B from LDS ----
        #pragma unroll
        for (int tap = 0; tap < 9; ++tap) {
            int ky = tap / 3, kx = tap % 3;
            int p0 = (row_w + ky) * 130 + col0 + kx + lanep;
            int bo = p0 * 32 + (hi ^ ((p0 >> 1) & 3)) * 8;
            frag16 bf[4];
            #pragma unroll
            for (int n = 0; n < 4; ++n)
                bf[n] = *(const frag16*)(L + bo + n * 512);
            #pragma unroll
            for (int m = 0; m < 4; ++m)
                #pragma unroll
                for (int n = 0; n < 4; ++n)
                    acc[m][n] = __builtin_amdgcn_mfma_f32_16x16x32_bf16(wr_[tap][m], bf[n], acc[m][n], 0, 0, 0);
        }
        __syncthreads();   // X reads complete before next chunk overwrites
    }

    // ---- epilogue: bias + tanh + per-class partial sums (part aliases L) ----
    float bv[4][4];
    #pragma unroll
    for (int m = 0; m < 4; ++m)
        #pragma unroll
        for (int r = 0; r < 4; ++r)
            bv[m][r] = bias[cob + m * 16 + hi * 4 + r];

    for (int e = t; e < S * 64; e += 256) part[e] = 0.f;
    __syncthreads();

    int y = y0 + row_w;
    #pragma unroll
    for (int n = 0; n < 4; ++n) {
        int x = col0 + n * 16 + lanep;
        int s = lab[(b << 14) + (y << 7) + x];
        #pragma unroll
        for (int m = 0; m < 4; ++m)
            #pragma unroll
            for (int r = 0; r < 4; ++r)
                atomicAdd(&part[s * 64 + m * 16 + hi * 4 + r], tanhf(acc[m][n][r] + bv[m][r]));
    }
    __syncthreads();
    for (int e = t; e < S * 64; e += 256) {
        int s = e >> 6, col = e & 63;
        atomicAdd(&sumbuf[((b * S + s) << 9) + cob + col], part[e]);
    }
}

// ---------------- finalize ----------------
__global__ LB void k_final(const float* __restrict__ sumbuf, const int* __restrict__ counts,
                           float* __restrict__ out) {
    int idx = blockIdx.x * 256 + threadIdx.x;   // 8*19*512
    int tt = idx >> 9;
    int s = tt % S, b = tt / S;
    int cnt = counts[b * S + s];
    out[idx] = cnt > 0 ? sumbuf[idx] / (float)cnt : 0.f;
}

extern "C" void kernel_launch(void* const* d_in, const int* in_sizes, int n_in,
                              void* d_out, int out_size, void* d_ws, size_t ws_size,
                              hipStream_t stream) {
    const float* input  = (const float*)d_in[0];
    const float* segmap = (const float*)d_in[1];
    const float* w1 = (const float*)d_in[2];  const float* b1 = (const float*)d_in[3];
    const float* w2 = (const float*)d_in[4];  const float* b2 = (const float*)d_in[5];
    const float* w3 = (const float*)d_in[6];  const float* b3 = (const float*)d_in[7];
    const float* w4 = (const float*)d_in[8];  const float* b4 = (const float*)d_in[9];
    const float* w5 = (const float*)d_in[10]; const float* b5 = (const float*)d_in[11];
    float* out = (float*)d_out;

    float* ws = (float*)d_ws;
    ushort* xl    = (ushort*)ws;                  // [8,128,128,256] bf16
    ushort* x1l   = (ushort*)(ws + 16777216);     // [8,256,256,32]
    ushort* x2l   = (ushort*)(ws + 25165824);     // [8,128,128,64]
    ushort* x3l   = (ushort*)(ws + 29360128);     // [8,64,64,128]
    int*   lab    = (int*)(ws + 31539200);        // 131,072
    ushort* wt5   = (ushort*)(ws + 31670528);     // 1,179,648 bf16
    ushort* wt4t  = (ushort*)(ws + 32260352);     // 294,912 bf16
    ushort* wt2   = (ushort*)(ws + 32407808);     // 18,432 bf16
    ushort* wt3   = (ushort*)(ws + 32417024);     // 73,728 bf16
    // zero region (contiguous, cleared by k_prep): sumbuf, counts, stat accumulators
    float* zbase  = ws + 32453888;
    float* sumbuf = zbase;                        // 77,824
    int*   counts = (int*)(zbase + 77824);        // 256
    float* ps1    = zbase + 78080;                // 256
    float* qs1    = zbase + 78336;                // 256
    float* ps2    = zbase + 78592;                // 512
    float* qs2    = zbase + 79104;                // 512
    float* ps3    = zbase + 79616;                // 1,024
    float* qs3    = zbase + 80640;                // 1,024
    float* ps4    = zbase + 81664;                // 2,048
    float* qs4    = zbase + 83712;                // 2,048
    const int ZN  = 85760;

    // prep: weight transposes + zero all accumulators
    k_prep<<<6120, 256, 0, stream>>>(w2, w3, w4, w5, wt2, wt3, wt4t, wt5, zbase, ZN);
    // layer 1 (+ fused label map; counts zeroed by k_prep above)
    k_conv1cl<<<2048, 256, 0, stream>>>(input, w1, b1, x1l, segmap, lab, counts);
    k_stats_cl<32, 1024, 64><<<512, 256, 0, stream>>>(x1l, ps1, qs1);
    k_nl_cl<32, 65536><<<8192, 256, 0, stream>>>(x1l, ps1, qs1);
    // layer 2
    k_conv2m<<<1024, 256, 0, stream>>>(x1l, wt2, b2, x2l);
    k_stats_cl<64, 512, 32><<<256, 256, 0, stream>>>(x2l, ps2, qs2);
    k_nl_cl<64, 16384><<<4096, 256, 0, stream>>>(x2l, ps2, qs2);
    // layer 3
    k_conv3m<<<512, 256, 0, stream>>>(x2l, wt3, b3, x3l);
    k_stats_cl<128, 256, 16><<<128, 256, 0, stream>>>(x3l, ps3, qs3);
    k_nl_cl<128, 4096><<<2048, 256, 0, stream>>>(x3l, ps3, qs3);
    // layer 4 (transpose conv)
    k_convt4m<<<2048, 256, 0, stream>>>(x3l, wt4t, b4, xl);
    k_stats_cl<256, 512, 32><<<256, 256, 0, stream>>>(xl, ps4, qs4);
    k_nl_cl<256, 16384><<<16384, 256, 0, stream>>>(xl, ps4, qs4);
    // layer 5: MFMA implicit GEMM v11 (X gll16 single-buffer, W in regs) + class-sum
    k_conv5m<<<4096, 256, 0, stream>>>(xl, wt5, b5, lab, sumbuf);
    // finalize
    k_final<<<304, 256, 0, stream>>>(sumbuf, counts, out);
}

// Round 16
// 1209.640 us; speedup vs baseline: 1.0004x; 1.0004x over previous
//
#include <hip/hip_runtime.h>

#define LB __launch_bounds__(256)

constexpr int S = 19;

typedef __attribute__((ext_vector_type(8))) short frag16;   // 8 bf16 (4 VGPR)
typedef __attribute__((ext_vector_type(8))) ushort ushort8;
typedef __attribute__((ext_vector_type(4))) float f32x4;

__device__ __forceinline__ int reflect256(int i) { return i < 0 ? -i : (i > 255 ? 510 - i : i); }
__device__ __forceinline__ int reflect128(int i) { return i < 0 ? -i : (i > 127 ? 254 - i : i); }

__device__ __forceinline__ ushort f2bf(float f) {
    union { float f; uint u; } a; a.f = f;
    uint r = a.u + 0x7fffu + ((a.u >> 16) & 1u);   // round-nearest-even
    return (ushort)(r >> 16);
}
__device__ __forceinline__ float bf2f(ushort u) {
    union { uint u; float f; } a; a.u = ((uint)u) << 16; return a.f;
}

// async global->LDS, 16B per lane; LDS dest = wave-uniform base + lane*16 (linear)
__device__ __forceinline__ void gll16(const void* g, void* l) {
    __builtin_amdgcn_global_load_lds(
        (const __attribute__((address_space(1))) void*)g,
        (__attribute__((address_space(3))) void*)l, 16, 0, 0);
}

// ---------------- prep: weight transposes + zero accumulator region ----------------
__global__ LB void k_prep(const float* __restrict__ w2, const float* __restrict__ w3,
                          const float* __restrict__ w4, const float* __restrict__ w5,
                          ushort* __restrict__ t2, ushort* __restrict__ t3,
                          ushort* __restrict__ t4, ushort* __restrict__ t5,
                          float* __restrict__ zf, int ZN) {
    int e = blockIdx.x * 256 + threadIdx.x;    // 1,566,720 total
    if (e < ZN) zf[e] = 0.f;
    if (e < 18432) {
        int ci = e & 31, co = (e >> 5) & 63, tap = e >> 11;
        t2[e] = f2bf(w2[(co * 32 + ci) * 9 + tap]);
    } else if (e < 18432 + 73728) {
        int e2 = e - 18432;
        int ci = e2 & 63, co = (e2 >> 6) & 127, tap = e2 >> 13;
        t3[e2] = f2bf(w3[(co * 64 + ci) * 9 + tap]);
    } else if (e < 18432 + 73728 + 294912) {
        int e3 = e - (18432 + 73728);
        int ci = e3 & 127, co = (e3 >> 7) & 255, tap = e3 >> 15;
        t4[e3] = f2bf(w4[ci * 2304 + co * 9 + tap]);   // w4 is (Cin,Cout,kh,kw)
    } else {
        int e4 = e - (18432 + 73728 + 294912);
        int ci = e4 & 255, co = (e4 >> 8) & 511, tap = e4 >> 17;
        t5[e4] = f2bf(w5[(co * 256 + ci) * 9 + tap]);
    }
}

// ---------------- conv1 (+ fused label map): [8,3,256,256] f32 -> [8,256,256,32] bf16 CL ----
// blocks 0..511 additionally compute the 128x128 nearest-resize label map + class counts
// (counts was zeroed by k_prep, which precedes this kernel in stream order).
__global__ LB void k_conv1cl(const float* __restrict__ in, const float* __restrict__ w,
                             const float* __restrict__ bias, ushort* __restrict__ out,
                             const float* __restrict__ segmap, int* __restrict__ lab,
                             int* __restrict__ counts) {
    __shared__ float Wr[864];   // [co][ci*9+tap]
    __shared__ float Bs[32];
    __shared__ int h[S];
    int t = threadIdx.x;
    int bx = blockIdx.x;
    for (int e = t; e < 864; e += 256) Wr[e] = w[e];
    if (t < 32) Bs[t] = bias[t];
    if (t < S) h[t] = 0;
    __syncthreads();
    int idx = bx * 256 + t;          // 524288 pixels
    int x = idx & 255, y = (idx >> 8) & 255, b = idx >> 16;
    float v[27];
    #pragma unroll
    for (int ci = 0; ci < 3; ++ci) {
        const float* ip = in + ((b * 3 + ci) << 16);
        #pragma unroll
        for (int ky = 0; ky < 3; ++ky) {
            int iy = reflect256(y + ky - 1);
            #pragma unroll
            for (int kx = 0; kx < 3; ++kx) {
                int ix = reflect256(x + kx - 1);
                v[ci * 9 + ky * 3 + kx] = ip[(iy << 8) + ix];
            }
        }
    }
    ushort* op = out + (long)idx * 32;
    #pragma unroll
    for (int g = 0; g < 4; ++g) {
        ushort8 o;
        #pragma unroll
        for (int j = 0; j < 8; ++j) {
            int co = g * 8 + j;
            float a = Bs[co];
            #pragma unroll
            for (int k = 0; k < 27; ++k) a += v[k] * Wr[co * 27 + k];
            o[j] = f2bf(a);
        }
        *(ushort8*)(op + g * 8) = o;
    }
    // ---- fused label map (blocks 0..511 cover 8*128*128 sites) ----
    if (bx < 512) {
        int i2 = bx * 256 + t;
        int lx = i2 & 127, ly = (i2 >> 7) & 127, lb = i2 >> 14;
        const float* sp = segmap + (long)lb * S * 65536 + (ly << 1) * 256 + (lx << 1);
        int s = 0;
        for (int c = 0; c < S; ++c) {
            if (sp[c * 65536] > 0.f) { s = c; break; }
        }
        lab[i2] = s;
        atomicAdd(&h[s], 1);
        __syncthreads();
        if (t < S) atomicAdd(&counts[lb * S + t], h[t]);
    }
}

// ---------------- channels-last instance-norm: block partials -> global atomic accum ----
template <int C, int PB, int SPLITS>
__global__ LB void k_stats_cl(const ushort* __restrict__ x,
                              float* __restrict__ psum, float* __restrict__ pss) {
    __shared__ float lsum[C], lss[C];
    int b = blockIdx.x / SPLITS, sp = blockIdx.x % SPLITS;
    int t = threadIdx.x;
    if (t < C) { lsum[t] = 0.f; lss[t] = 0.f; }
    __syncthreads();
    constexpr int CG = C / 8;
    constexpr int PO = 256 / CG;
    int c0 = (t % CG) * 8;
    int po = t / CG;
    float s[8], ss[8];
    #pragma unroll
    for (int k = 0; k < 8; ++k) { s[k] = 0.f; ss[k] = 0.f; }
    const ushort* base = x + ((long)b * SPLITS + sp) * (long)PB * C;
    for (int p = po; p < PB; p += PO) {
        ushort8 v = *(const ushort8*)(base + (long)p * C + c0);
        #pragma unroll
        for (int k = 0; k < 8; ++k) {
            float f = bf2f(v[k]);
            s[k] += f; ss[k] += f * f;
        }
    }
    #pragma unroll
    for (int k = 0; k < 8; ++k) {
        atomicAdd(&lsum[c0 + k], s[k]);
        atomicAdd(&lss[c0 + k], ss[k]);
    }
    __syncthreads();
    if (t < C) {
        atomicAdd(&psum[b * C + t], lsum[t]);
        atomicAdd(&pss[b * C + t], lss[t]);
    }
}

// ---------------- normalize + leaky-relu in place; mean/istd computed in-block ----------
template <int C, int P>
__global__ LB void k_nl_cl(ushort* __restrict__ x, const float* __restrict__ psum,
                           const float* __restrict__ pss) {
    __shared__ float M[C], I[C];
    int t = threadIdx.x;
    long e0 = (long)blockIdx.x * 2048;         // elements per block
    int b = (int)(e0 / ((long)P * C));
    if (t < C) {
        float s = psum[b * C + t], q = pss[b * C + t];
        float m = s / (float)P;
        float v = q / (float)P - m * m;
        M[t] = m;
        I[t] = rsqrtf(v + 1e-5f);
    }
    __syncthreads();
    long e = e0 + t * 8;
    int c0 = (int)(e % C);
    ushort8 v = *(ushort8*)(x + e);
    #pragma unroll
    for (int k = 0; k < 8; ++k) {
        float u = (bf2f(v[k]) - M[c0 + k]) * I[c0 + k];
        u = u > 0.f ? u : 0.2f * u;
        v[k] = f2bf(u);
    }
    *(ushort8*)(x + e) = v;
}

// ---------------- conv2 MFMA: [8,256,256,32] -> [8,128,128,64], s2 p1 zero-pad ----------------
__global__ LB void k_conv2m(const ushort* __restrict__ xin, const ushort* __restrict__ wt,
                            const float* __restrict__ bias, ushort* __restrict__ xout) {
    int bx = blockIdx.x;
    int y = bx & 127, b = bx >> 7;
    int t = threadIdx.x, w = t >> 6, lane = t & 63;
    int col0 = w * 32;
    int lanep = lane & 15, hi = lane >> 4;

    f32x4 acc[4][2];
    #pragma unroll
    for (int m = 0; m < 4; ++m)
        #pragma unroll
        for (int n = 0; n < 2; ++n) acc[m][n] = (f32x4){0.f, 0.f, 0.f, 0.f};

    #pragma unroll
    for (int ky = 0; ky < 3; ++ky) {
        int iy = 2 * y + ky - 1;
        if (iy < 0) continue;
        #pragma unroll
        for (int kx = 0; kx < 3; ++kx) {
            int tap = ky * 3 + kx;
            const ushort* wb = wt + ((tap * 64 + lanep) << 5) + hi * 8;
            frag16 av[4];
            #pragma unroll
            for (int m = 0; m < 4; ++m) av[m] = *(const frag16*)(wb + ((m * 16) << 5));
            frag16 bv[2];
            #pragma unroll
            for (int n = 0; n < 2; ++n) {
                int xo = col0 + n * 16 + lanep;
                int ix = 2 * xo + kx - 1;
                frag16 vv = (frag16)(short)0;
                if (ix >= 0)
                    vv = *(const frag16*)(xin + ((((long)(b * 256 + iy)) << 8) + ix) * 32 + hi * 8);
                bv[n] = vv;
            }
            #pragma unroll
            for (int m = 0; m < 4; ++m)
                #pragma unroll
                for (int n = 0; n < 2; ++n)
                    acc[m][n] = __builtin_amdgcn_mfma_f32_16x16x32_bf16(av[m], bv[n], acc[m][n], 0, 0, 0);
        }
    }
    float bvv[4][4];
    #pragma unroll
    for (int m = 0; m < 4; ++m)
        #pragma unroll
        for (int r = 0; r < 4; ++r) bvv[m][r] = bias[m * 16 + hi * 4 + r];
    #pragma unroll
    for (int n = 0; n < 2; ++n) {
        int xo = col0 + n * 16 + lanep;
        long pb = ((((long)(b * 128 + y)) << 7) + xo) * 64 + hi * 4;
        #pragma unroll
        for (int m = 0; m < 4; ++m) {
            ushort4 o;
            o.x = f2bf(acc[m][n][0] + bvv[m][0]);
            o.y = f2bf(acc[m][n][1] + bvv[m][1]);
            o.z = f2bf(acc[m][n][2] + bvv[m][2]);
            o.w = f2bf(acc[m][n][3] + bvv[m][3]);
            *(ushort4*)(xout + pb + m * 16) = o;
        }
    }
}

// ---------------- conv3 MFMA: [8,128,128,64] -> [8,64,64,128], s2 p1 zero-pad ----------------
__global__ LB void k_conv3m(const ushort* __restrict__ xin, const ushort* __restrict__ wt,
                            const float* __restrict__ bias, ushort* __restrict__ xout) {
    int bx = blockIdx.x;
    int y = bx & 63, b = bx >> 6;
    int t = threadIdx.x, w = t >> 6, lane = t & 63;
    int co0 = (w >> 1) * 64;
    int col0 = (w & 1) * 32;
    int lanep = lane & 15, hi = lane >> 4;

    f32x4 acc[4][2];
    #pragma unroll
    for (int m = 0; m < 4; ++m)
        #pragma unroll
        for (int n = 0; n < 2; ++n) acc[m][n] = (f32x4){0.f, 0.f, 0.f, 0.f};

    #pragma unroll
    for (int ky = 0; ky < 3; ++ky) {
        int iy = 2 * y + ky - 1;
        if (iy < 0) continue;
        #pragma unroll
        for (int kx = 0; kx < 3; ++kx) {
            int tap = ky * 3 + kx;
            #pragma unroll
            for (int ck = 0; ck < 2; ++ck) {
                int ci0 = ck * 32;
                const ushort* wb = wt + ((tap * 128 + co0 + lanep) << 6) + ci0 + hi * 8;
                frag16 av[4];
                #pragma unroll
                for (int m = 0; m < 4; ++m) av[m] = *(const frag16*)(wb + ((m * 16) << 6));
                frag16 bv[2];
                #pragma unroll
                for (int n = 0; n < 2; ++n) {
                    int xo = col0 + n * 16 + lanep;
                    int ix = 2 * xo + kx - 1;
                    frag16 vv = (frag16)(short)0;
                    if (ix >= 0)
                        vv = *(const frag16*)(xin + ((((long)(b * 128 + iy)) << 7) + ix) * 64 + ci0 + hi * 8);
                    bv[n] = vv;
                }
                #pragma unroll
                for (int m = 0; m < 4; ++m)
                    #pragma unroll
                    for (int n = 0; n < 2; ++n)
                        acc[m][n] = __builtin_amdgcn_mfma_f32_16x16x32_bf16(av[m], bv[n], acc[m][n], 0, 0, 0);
            }
        }
    }
    float bvv[4][4];
    #pragma unroll
    for (int m = 0; m < 4; ++m)
        #pragma unroll
        for (int r = 0; r < 4; ++r) bvv[m][r] = bias[co0 + m * 16 + hi * 4 + r];
    #pragma unroll
    for (int n = 0; n < 2; ++n) {
        int xo = col0 + n * 16 + lanep;
        long pb = ((((long)(b * 64 + y)) << 6) + xo) * 128 + co0 + hi * 4;
        #pragma unroll
        for (int m = 0; m < 4; ++m) {
            ushort4 o;
            o.x = f2bf(acc[m][n][0] + bvv[m][0]);
            o.y = f2bf(acc[m][n][1] + bvv[m][1]);
            o.z = f2bf(acc[m][n][2] + bvv[m][2]);
            o.w = f2bf(acc[m][n][3] + bvv[m][3]);
            *(ushort4*)(xout + pb + m * 16) = o;
        }
    }
}

// ---------------- convT4 MFMA (parity decomposition): [8,64,64,128] -> [8,128,128,256] ----
__global__ LB void k_convt4m(const ushort* __restrict__ x3l, const ushort* __restrict__ wt,
                             const float* __restrict__ bias, ushort* __restrict__ xl) {
    int bx = blockIdx.x;
    int parity = bx & 3;
    int py = parity >> 1, px = parity & 1;
    int rg = (bx >> 2) & 15;
    int ct = (bx >> 6) & 3;
    int b  = bx >> 8;
    int co0 = ct * 64;
    int t = threadIdx.x;
    int w = t >> 6;
    int ip = rg * 4 + w;
    int lane = t & 63;
    int lanep = lane & 15;
    int hi = lane >> 4;
    int laneq = hi * 8;

    f32x4 acc[4][4];
    #pragma unroll
    for (int m = 0; m < 4; ++m)
        #pragma unroll
        for (int n = 0; n < 4; ++n) acc[m][n] = (f32x4){0.f, 0.f, 0.f, 0.f};

    #pragma unroll
    for (int ky = 0; ky < 3; ++ky) {
        if (((ky + py) & 1) == 0) continue;
        int i = ip + ((py == 1 && ky == 0) ? 1 : 0);
        if (i >= 64) continue;
        #pragma unroll
        for (int kx = 0; kx < 3; ++kx) {
            if (((kx + px) & 1) == 0) continue;
            int dxp = (px == 1 && kx == 0) ? 1 : 0;
            int tap = ky * 3 + kx;
            const ushort* wbase = wt + (((long)tap * 256 + co0 + lanep) << 7) + laneq;
            const ushort* xbase = x3l + ((((long)b << 12) + (i << 6)) << 7) + laneq;
            #pragma unroll
            for (int ci0 = 0; ci0 < 128; ci0 += 32) {
                frag16 av[4], bv[4];
                #pragma unroll
                for (int m = 0; m < 4; ++m)
                    av[m] = *(const frag16*)(wbase + ((m * 16) << 7) + ci0);
                #pragma unroll
                for (int n = 0; n < 4; ++n) {
                    int j = n * 16 + lanep + dxp;
                    bool valid = j < 64;
                    frag16 v = *(const frag16*)(xbase + ((valid ? j : 63) << 7) + ci0);
                    if (!valid) v = (frag16)(short)0;
                    bv[n] = v;
                }
                #pragma unroll
                for (int m = 0; m < 4; ++m)
                    #pragma unroll
                    for (int n = 0; n < 4; ++n)
                        acc[m][n] = __builtin_amdgcn_mfma_f32_16x16x32_bf16(av[m], bv[n], acc[m][n], 0, 0, 0);
            }
        }
    }

    float bvv[4][4];
    #pragma unroll
    for (int m = 0; m < 4; ++m)
        #pragma unroll
        for (int r = 0; r < 4; ++r)
            bvv[m][r] = bias[co0 + m * 16 + hi * 4 + r];
    int y = 2 * ip + py;
    #pragma unroll
    for (int n = 0; n < 4; ++n) {
        int x = 2 * (n * 16 + lanep) + px;
        long pb = ((((long)b << 14) + (y << 7) + x) << 8) + co0 + hi * 4;
        #pragma unroll
        for (int m = 0; m < 4; ++m) {
            ushort4 o;
            o.x = f2bf(acc[m][n][0] + bvv[m][0]);
            o.y = f2bf(acc[m][n][1] + bvv[m][1]);
            o.z = f2bf(acc[m][n][2] + bvv[m][2]);
            o.w = f2bf(acc[m][n][3] + bvv[m][3]);
            *(ushort4*)(xl + pb + m * 16) = o;
        }
    }
}

// ---------------- conv5 MFMA implicit GEMM v11: X via gll16 single-buffer, W in registers ----
// xl: [8][128][128][256] bf16; wt: [9][512][256] bf16
// block (256 thr, 4 waves): b, co-tile 64 (ct 0..7), row-pair (yp 0..63).
// LDS: X only (33,280B) + part alias. Per chunk: issue 8 X glls + load 36 W frags to regs
// (statically indexed, rule #20); barrier drains both; compute reads A from regs, B from LDS.
// VGPR ~ 144(W) + 64(acc) + ~35 misc <= 256 cap at (256,2) -> no spill, 2 blocks/CU.
__global__ void __launch_bounds__(256, 2)
k_conv5m(const ushort* __restrict__ xl, const ushort* __restrict__ wt,
         const float* __restrict__ bias, const int* __restrict__ lab,
         float* __restrict__ sumbuf) {
    __shared__ __align__(16) ushort L[16640];
    float* part = (float*)L;                 // aliased in epilogue (4,864 B)

    int bx = blockIdx.x;
    int yp = bx & 63;
    int ct = (bx >> 6) & 7;
    int b  = bx >> 9;
    int y0 = yp * 2, cob = ct * 64;
    int t = threadIdx.x;
    int w = t >> 6;
    int lane = t & 63;
    int row_w = w & 1;
    int col0 = (w >> 1) * 64;
    int lanep = lane & 15;
    int hi = lane >> 4;
    int laneq = hi * 8;

    // ---- X staging offsets (swizzled global source, linear LDS dest; rule #21) ----
    long xbase = (long)b << 14;
    int xg[9];
    #pragma unroll
    for (int k = 0; k < 9; ++k) {
        int e = t + k * 256;
        int q = e & 3, p = e >> 2;
        int qp = q ^ ((p >> 1) & 3);
        if (e < 2080) {
            int r = p / 130, c = p - r * 130;
            int gy = reflect128(y0 - 1 + r);
            int gc = reflect128(c - 1);
            xg[k] = (int)(((xbase + (gy << 7) + gc) << 8) + qp * 8);
        } else xg[k] = (int)(xbase << 8);       // never issued
    }
    // ---- W per-lane fragment addresses (A-frag layout): + tap*131072 + ci0 at use ----
    int wbo[4];
    #pragma unroll
    for (int m = 0; m < 4; ++m)
        wbo[m] = ((cob + m * 16 + lanep) << 8) + laneq;

    f32x4 acc[4][4];
    #pragma unroll
    for (int m = 0; m < 4; ++m)
        #pragma unroll
        for (int n = 0; n < 4; ++n) acc[m][n] = (f32x4){0.f, 0.f, 0.f, 0.f};

    frag16 wr_[9][4];

    #pragma unroll 1
    for (int c8 = 0; c8 < 8; ++c8) {
        int cin = c8 * 32;
        // ---- stage X chunk (async to LDS) + W chunk (to registers) ----
        #pragma unroll
        for (int k = 0; k < 8; ++k) gll16(xl + xg[k] + cin, L + ((k << 8) + t) * 8);
        if (t < 32) gll16(xl + xg[8] + cin, L + ((8 << 8) + t) * 8);
        #pragma unroll
        for (int tap = 0; tap < 9; ++tap)
            #pragma unroll
            for (int m = 0; m < 4; ++m)
                wr_[tap][m] = *(const frag16*)(wt + tap * 131072 + wbo[m] + cin);
        __syncthreads();   // drains vmcnt(0): X in LDS, W in regs
        // ---- compute 9 taps: A from regs, B from LDS ----
        #pragma unroll
        for (int tap = 0; tap < 9; ++tap) {
            int ky = tap / 3, kx = tap % 3;
            int p0 = (row_w + ky) * 130 + col0 + kx + lanep;
            int bo = p0 * 32 + (hi ^ ((p0 >> 1) & 3)) * 8;
            frag16 bf[4];
            #pragma unroll
            for (int n = 0; n < 4; ++n)
                bf[n] = *(const frag16*)(L + bo + n * 512);
            #pragma unroll
            for (int m = 0; m < 4; ++m)
                #pragma unroll
                for (int n = 0; n < 4; ++n)
                    acc[m][n] = __builtin_amdgcn_mfma_f32_16x16x32_bf16(wr_[tap][m], bf[n], acc[m][n], 0, 0, 0);
        }
        __syncthreads();   // X reads complete before next chunk overwrites
    }

    // ---- epilogue: bias + tanh + per-class partial sums (part aliases L) ----
    float bv[4][4];
    #pragma unroll
    for (int m = 0; m < 4; ++m)
        #pragma unroll
        for (int r = 0; r < 4; ++r)
            bv[m][r] = bias[cob + m * 16 + hi * 4 + r];

    for (int e = t; e < S * 64; e += 256) part[e] = 0.f;
    __syncthreads();

    int y = y0 + row_w;
    #pragma unroll
    for (int n = 0; n < 4; ++n) {
        int x = col0 + n * 16 + lanep;
        int s = lab[(b << 14) + (y << 7) + x];
        #pragma unroll
        for (int m = 0; m < 4; ++m)
            #pragma unroll
            for (int r = 0; r < 4; ++r)
                atomicAdd(&part[s * 64 + m * 16 + hi * 4 + r], tanhf(acc[m][n][r] + bv[m][r]));
    }
    __syncthreads();
    for (int e = t; e < S * 64; e += 256) {
        int s = e >> 6, col = e & 63;
        atomicAdd(&sumbuf[((b * S + s) << 9) + cob + col], part[e]);
    }
}

// ---------------- finalize ----------------
__global__ LB void k_final(const float* __restrict__ sumbuf, const int* __restrict__ counts,
                           float* __restrict__ out) {
    int idx = blockIdx.x * 256 + threadIdx.x;   // 8*19*512
    int tt = idx >> 9;
    int s = tt % S, b = tt / S;
    int cnt = counts[b * S + s];
    out[idx] = cnt > 0 ? sumbuf[idx] / (float)cnt : 0.f;
}

extern "C" void kernel_launch(void* const* d_in, const int* in_sizes, int n_in,
                              void* d_out, int out_size, void* d_ws, size_t ws_size,
                              hipStream_t stream) {
    const float* input  = (const float*)d_in[0];
    const float* segmap = (const float*)d_in[1];
    const float* w1 = (const float*)d_in[2];  const float* b1 = (const float*)d_in[3];
    const float* w2 = (const float*)d_in[4];  const float* b2 = (const float*)d_in[5];
    const float* w3 = (const float*)d_in[6];  const float* b3 = (const float*)d_in[7];
    const float* w4 = (const float*)d_in[8];  const float* b4 = (const float*)d_in[9];
    const float* w5 = (const float*)d_in[10]; const float* b5 = (const float*)d_in[11];
    float* out = (float*)d_out;

    float* ws = (float*)d_ws;
    ushort* xl    = (ushort*)ws;                  // [8,128,128,256] bf16
    ushort* x1l   = (ushort*)(ws + 16777216);     // [8,256,256,32]
    ushort* x2l   = (ushort*)(ws + 25165824);     // [8,128,128,64]
    ushort* x3l   = (ushort*)(ws + 29360128);     // [8,64,64,128]
    int*   lab    = (int*)(ws + 31539200);        // 131,072
    ushort* wt5   = (ushort*)(ws + 31670528);     // 1,179,648 bf16
    ushort* wt4t  = (ushort*)(ws + 32260352);     // 294,912 bf16
    ushort* wt2   = (ushort*)(ws + 32407808);     // 18,432 bf16
    ushort* wt3   = (ushort*)(ws + 32417024);     // 73,728 bf16
    // zero region (contiguous, cleared by k_prep): sumbuf, counts, stat accumulators
    float* zbase  = ws + 32453888;
    float* sumbuf = zbase;                        // 77,824
    int*   counts = (int*)(zbase + 77824);        // 256
    float* ps1    = zbase + 78080;                // 256
    float* qs1    = zbase + 78336;                // 256
    float* ps2    = zbase + 78592;                // 512
    float* qs2    = zbase + 79104;                // 512
    float* ps3    = zbase + 79616;                // 1,024
    float* qs3    = zbase + 80640;                // 1,024
    float* ps4    = zbase + 81664;                // 2,048
    float* qs4    = zbase + 83712;                // 2,048
    const int ZN  = 85760;

    // prep: weight transposes + zero all accumulators
    k_prep<<<6120, 256, 0, stream>>>(w2, w3, w4, w5, wt2, wt3, wt4t, wt5, zbase, ZN);
    // layer 1 (+ fused label map; counts zeroed by k_prep above)
    k_conv1cl<<<2048, 256, 0, stream>>>(input, w1, b1, x1l, segmap, lab, counts);
    k_stats_cl<32, 1024, 64><<<512, 256, 0, stream>>>(x1l, ps1, qs1);
    k_nl_cl<32, 65536><<<8192, 256, 0, stream>>>(x1l, ps1, qs1);
    // layer 2
    k_conv2m<<<1024, 256, 0, stream>>>(x1l, wt2, b2, x2l);
    k_stats_cl<64, 512, 32><<<256, 256, 0, stream>>>(x2l, ps2, qs2);
    k_nl_cl<64, 16384><<<4096, 256, 0, stream>>>(x2l, ps2, qs2);
    // layer 3
    k_conv3m<<<512, 256, 0, stream>>>(x2l, wt3, b3, x3l);
    k_stats_cl<128, 256, 16><<<128, 256, 0, stream>>>(x3l, ps3, qs3);
    k_nl_cl<128, 4096><<<2048, 256, 0, stream>>>(x3l, ps3, qs3);
    // layer 4 (transpose conv)
    k_convt4m<<<2048, 256, 0, stream>>>(x3l, wt4t, b4, xl);
    k_stats_cl<256, 512, 32><<<256, 256, 0, stream>>>(xl, ps4, qs4);
    k_nl_cl<256, 16384><<<16384, 256, 0, stream>>>(xl, ps4, qs4);
    // layer 5: MFMA implicit GEMM v11 (X gll16 single-buffer, W in regs) + class-sum
    k_conv5m<<<4096, 256, 0, stream>>>(xl, wt5, b5, lab, sumbuf);
    // finalize
    k_final<<<304, 256, 0, stream>>>(sumbuf, counts, out);
}

// Round 17
// 883.624 us; speedup vs baseline: 1.3695x; 1.3690x over previous
//
#include <hip/hip_runtime.h>

#define LB __launch_bounds__(256)

constexpr int S = 19;

typedef __attribute__((ext_vector_type(8))) short frag16;   // 8 bf16 (4 VGPR)
typedef __attribute__((ext_vector_type(8))) ushort ushort8;
typedef __attribute__((ext_vector_type(4))) float f32x4;

__device__ __forceinline__ int reflect256(int i) { return i < 0 ? -i : (i > 255 ? 510 - i : i); }
__device__ __forceinline__ int reflect128(int i) { return i < 0 ? -i : (i > 127 ? 254 - i : i); }

__device__ __forceinline__ ushort f2bf(float f) {
    union { float f; uint u; } a; a.f = f;
    uint r = a.u + 0x7fffu + ((a.u >> 16) & 1u);   // round-nearest-even
    return (ushort)(r >> 16);
}
__device__ __forceinline__ float bf2f(ushort u) {
    union { uint u; float f; } a; a.u = ((uint)u) << 16; return a.f;
}

// async global->LDS, 16B per lane; LDS dest = wave-uniform base + lane*16 (linear)
__device__ __forceinline__ void gll16(const void* g, void* l) {
    __builtin_amdgcn_global_load_lds(
        (const __attribute__((address_space(1))) void*)g,
        (__attribute__((address_space(3))) void*)l, 16, 0, 0);
}

// ---------------- prep: weight transposes + zero accumulator region ----------------
__global__ LB void k_prep(const float* __restrict__ w2, const float* __restrict__ w3,
                          const float* __restrict__ w4, const float* __restrict__ w5,
                          ushort* __restrict__ t2, ushort* __restrict__ t3,
                          ushort* __restrict__ t4, ushort* __restrict__ t5,
                          float* __restrict__ zf, int ZN) {
    int e = blockIdx.x * 256 + threadIdx.x;    // 1,566,720 total
    if (e < ZN) zf[e] = 0.f;
    if (e < 18432) {
        int ci = e & 31, co = (e >> 5) & 63, tap = e >> 11;
        t2[e] = f2bf(w2[(co * 32 + ci) * 9 + tap]);
    } else if (e < 18432 + 73728) {
        int e2 = e - 18432;
        int ci = e2 & 63, co = (e2 >> 6) & 127, tap = e2 >> 13;
        t3[e2] = f2bf(w3[(co * 64 + ci) * 9 + tap]);
    } else if (e < 18432 + 73728 + 294912) {
        int e3 = e - (18432 + 73728);
        int ci = e3 & 127, co = (e3 >> 7) & 255, tap = e3 >> 15;
        t4[e3] = f2bf(w4[ci * 2304 + co * 9 + tap]);   // w4 is (Cin,Cout,kh,kw)
    } else {
        int e4 = e - (18432 + 73728 + 294912);
        int ci = e4 & 255, co = (e4 >> 8) & 511, tap = e4 >> 17;
        t5[e4] = f2bf(w5[(co * 256 + ci) * 9 + tap]);
    }
}

// ---------------- conv1 (+ fused label map): [8,3,256,256] f32 -> [8,256,256,32] bf16 CL ----
__global__ LB void k_conv1cl(const float* __restrict__ in, const float* __restrict__ w,
                             const float* __restrict__ bias, ushort* __restrict__ out,
                             const float* __restrict__ segmap, int* __restrict__ lab,
                             int* __restrict__ counts) {
    __shared__ float Wr[864];   // [co][ci*9+tap]
    __shared__ float Bs[32];
    __shared__ int h[S];
    int t = threadIdx.x;
    int bx = blockIdx.x;
    for (int e = t; e < 864; e += 256) Wr[e] = w[e];
    if (t < 32) Bs[t] = bias[t];
    if (t < S) h[t] = 0;
    __syncthreads();
    int idx = bx * 256 + t;          // 524288 pixels
    int x = idx & 255, y = (idx >> 8) & 255, b = idx >> 16;
    float v[27];
    #pragma unroll
    for (int ci = 0; ci < 3; ++ci) {
        const float* ip = in + ((b * 3 + ci) << 16);
        #pragma unroll
        for (int ky = 0; ky < 3; ++ky) {
            int iy = reflect256(y + ky - 1);
            #pragma unroll
            for (int kx = 0; kx < 3; ++kx) {
                int ix = reflect256(x + kx - 1);
                v[ci * 9 + ky * 3 + kx] = ip[(iy << 8) + ix];
            }
        }
    }
    ushort* op = out + (long)idx * 32;
    #pragma unroll
    for (int g = 0; g < 4; ++g) {
        ushort8 o;
        #pragma unroll
        for (int j = 0; j < 8; ++j) {
            int co = g * 8 + j;
            float a = Bs[co];
            #pragma unroll
            for (int k = 0; k < 27; ++k) a += v[k] * Wr[co * 27 + k];
            o[j] = f2bf(a);
        }
        *(ushort8*)(op + g * 8) = o;
    }
    // ---- fused label map (blocks 0..511 cover 8*128*128 sites) ----
    if (bx < 512) {
        int i2 = bx * 256 + t;
        int lx = i2 & 127, ly = (i2 >> 7) & 127, lb = i2 >> 14;
        const float* sp = segmap + (long)lb * S * 65536 + (ly << 1) * 256 + (lx << 1);
        int s = 0;
        for (int c = 0; c < S; ++c) {
            if (sp[c * 65536] > 0.f) { s = c; break; }
        }
        lab[i2] = s;
        atomicAdd(&h[s], 1);
        __syncthreads();
        if (t < S) atomicAdd(&counts[lb * S + t], h[t]);
    }
}

// ---------------- channels-last instance-norm: block partials -> global atomic accum ----
template <int C, int PB, int SPLITS>
__global__ LB void k_stats_cl(const ushort* __restrict__ x,
                              float* __restrict__ psum, float* __restrict__ pss) {
    __shared__ float lsum[C], lss[C];
    int b = blockIdx.x / SPLITS, sp = blockIdx.x % SPLITS;
    int t = threadIdx.x;
    if (t < C) { lsum[t] = 0.f; lss[t] = 0.f; }
    __syncthreads();
    constexpr int CG = C / 8;
    constexpr int PO = 256 / CG;
    int c0 = (t % CG) * 8;
    int po = t / CG;
    float s[8], ss[8];
    #pragma unroll
    for (int k = 0; k < 8; ++k) { s[k] = 0.f; ss[k] = 0.f; }
    const ushort* base = x + ((long)b * SPLITS + sp) * (long)PB * C;
    for (int p = po; p < PB; p += PO) {
        ushort8 v = *(const ushort8*)(base + (long)p * C + c0);
        #pragma unroll
        for (int k = 0; k < 8; ++k) {
            float f = bf2f(v[k]);
            s[k] += f; ss[k] += f * f;
        }
    }
    #pragma unroll
    for (int k = 0; k < 8; ++k) {
        atomicAdd(&lsum[c0 + k], s[k]);
        atomicAdd(&lss[c0 + k], ss[k]);
    }
    __syncthreads();
    if (t < C) {
        atomicAdd(&psum[b * C + t], lsum[t]);
        atomicAdd(&pss[b * C + t], lss[t]);
    }
}

// ---------------- normalize + leaky-relu in place; mean/istd computed in-block ----------
template <int C, int P>
__global__ LB void k_nl_cl(ushort* __restrict__ x, const float* __restrict__ psum,
                           const float* __restrict__ pss) {
    __shared__ float M[C], I[C];
    int t = threadIdx.x;
    long e0 = (long)blockIdx.x * 2048;         // elements per block
    int b = (int)(e0 / ((long)P * C));
    if (t < C) {
        float s = psum[b * C + t], q = pss[b * C + t];
        float m = s / (float)P;
        float v = q / (float)P - m * m;
        M[t] = m;
        I[t] = rsqrtf(v + 1e-5f);
    }
    __syncthreads();
    long e = e0 + t * 8;
    int c0 = (int)(e % C);
    ushort8 v = *(ushort8*)(x + e);
    #pragma unroll
    for (int k = 0; k < 8; ++k) {
        float u = (bf2f(v[k]) - M[c0 + k]) * I[c0 + k];
        u = u > 0.f ? u : 0.2f * u;
        v[k] = f2bf(u);
    }
    *(ushort8*)(x + e) = v;
}

// ---------------- conv2 MFMA: [8,256,256,32] -> [8,128,128,64], s2 p1 zero-pad ----------------
__global__ LB void k_conv2m(const ushort* __restrict__ xin, const ushort* __restrict__ wt,
                            const float* __restrict__ bias, ushort* __restrict__ xout) {
    int bx = blockIdx.x;
    int y = bx & 127, b = bx >> 7;
    int t = threadIdx.x, w = t >> 6, lane = t & 63;
    int col0 = w * 32;
    int lanep = lane & 15, hi = lane >> 4;

    f32x4 acc[4][2];
    #pragma unroll
    for (int m = 0; m < 4; ++m)
        #pragma unroll
        for (int n = 0; n < 2; ++n) acc[m][n] = (f32x4){0.f, 0.f, 0.f, 0.f};

    #pragma unroll
    for (int ky = 0; ky < 3; ++ky) {
        int iy = 2 * y + ky - 1;
        if (iy < 0) continue;
        #pragma unroll
        for (int kx = 0; kx < 3; ++kx) {
            int tap = ky * 3 + kx;
            const ushort* wb = wt + ((tap * 64 + lanep) << 5) + hi * 8;
            frag16 av[4];
            #pragma unroll
            for (int m = 0; m < 4; ++m) av[m] = *(const frag16*)(wb + ((m * 16) << 5));
            frag16 bv[2];
            #pragma unroll
            for (int n = 0; n < 2; ++n) {
                int xo = col0 + n * 16 + lanep;
                int ix = 2 * xo + kx - 1;
                frag16 vv = (frag16)(short)0;
                if (ix >= 0)
                    vv = *(const frag16*)(xin + ((((long)(b * 256 + iy)) << 8) + ix) * 32 + hi * 8);
                bv[n] = vv;
            }
            #pragma unroll
            for (int m = 0; m < 4; ++m)
                #pragma unroll
                for (int n = 0; n < 2; ++n)
                    acc[m][n] = __builtin_amdgcn_mfma_f32_16x16x32_bf16(av[m], bv[n], acc[m][n], 0, 0, 0);
        }
    }
    float bvv[4][4];
    #pragma unroll
    for (int m = 0; m < 4; ++m)
        #pragma unroll
        for (int r = 0; r < 4; ++r) bvv[m][r] = bias[m * 16 + hi * 4 + r];
    #pragma unroll
    for (int n = 0; n < 2; ++n) {
        int xo = col0 + n * 16 + lanep;
        long pb = ((((long)(b * 128 + y)) << 7) + xo) * 64 + hi * 4;
        #pragma unroll
        for (int m = 0; m < 4; ++m) {
            ushort4 o;
            o.x = f2bf(acc[m][n][0] + bvv[m][0]);
            o.y = f2bf(acc[m][n][1] + bvv[m][1]);
            o.z = f2bf(acc[m][n][2] + bvv[m][2]);
            o.w = f2bf(acc[m][n][3] + bvv[m][3]);
            *(ushort4*)(xout + pb + m * 16) = o;
        }
    }
}

// ---------------- conv3 MFMA: [8,128,128,64] -> [8,64,64,128], s2 p1 zero-pad ----------------
__global__ LB void k_conv3m(const ushort* __restrict__ xin, const ushort* __restrict__ wt,
                            const float* __restrict__ bias, ushort* __restrict__ xout) {
    int bx = blockIdx.x;
    int y = bx & 63, b = bx >> 6;
    int t = threadIdx.x, w = t >> 6, lane = t & 63;
    int co0 = (w >> 1) * 64;
    int col0 = (w & 1) * 32;
    int lanep = lane & 15, hi = lane >> 4;

    f32x4 acc[4][2];
    #pragma unroll
    for (int m = 0; m < 4; ++m)
        #pragma unroll
        for (int n = 0; n < 2; ++n) acc[m][n] = (f32x4){0.f, 0.f, 0.f, 0.f};

    #pragma unroll
    for (int ky = 0; ky < 3; ++ky) {
        int iy = 2 * y + ky - 1;
        if (iy < 0) continue;
        #pragma unroll
        for (int kx = 0; kx < 3; ++kx) {
            int tap = ky * 3 + kx;
            #pragma unroll
            for (int ck = 0; ck < 2; ++ck) {
                int ci0 = ck * 32;
                const ushort* wb = wt + ((tap * 128 + co0 + lanep) << 6) + ci0 + hi * 8;
                frag16 av[4];
                #pragma unroll
                for (int m = 0; m < 4; ++m) av[m] = *(const frag16*)(wb + ((m * 16) << 6));
                frag16 bv[2];
                #pragma unroll
                for (int n = 0; n < 2; ++n) {
                    int xo = col0 + n * 16 + lanep;
                    int ix = 2 * xo + kx - 1;
                    frag16 vv = (frag16)(short)0;
                    if (ix >= 0)
                        vv = *(const frag16*)(xin + ((((long)(b * 128 + iy)) << 7) + ix) * 64 + ci0 + hi * 8);
                    bv[n] = vv;
                }
                #pragma unroll
                for (int m = 0; m < 4; ++m)
                    #pragma unroll
                    for (int n = 0; n < 2; ++n)
                        acc[m][n] = __builtin_amdgcn_mfma_f32_16x16x32_bf16(av[m], bv[n], acc[m][n], 0, 0, 0);
            }
        }
    }
    float bvv[4][4];
    #pragma unroll
    for (int m = 0; m < 4; ++m)
        #pragma unroll
        for (int r = 0; r < 4; ++r) bvv[m][r] = bias[co0 + m * 16 + hi * 4 + r];
    #pragma unroll
    for (int n = 0; n < 2; ++n) {
        int xo = col0 + n * 16 + lanep;
        long pb = ((((long)(b * 64 + y)) << 6) + xo) * 128 + co0 + hi * 4;
        #pragma unroll
        for (int m = 0; m < 4; ++m) {
            ushort4 o;
            o.x = f2bf(acc[m][n][0] + bvv[m][0]);
            o.y = f2bf(acc[m][n][1] + bvv[m][1]);
            o.z = f2bf(acc[m][n][2] + bvv[m][2]);
            o.w = f2bf(acc[m][n][3] + bvv[m][3]);
            *(ushort4*)(xout + pb + m * 16) = o;
        }
    }
}

// ---------------- convT4 MFMA (parity decomposition): [8,64,64,128] -> [8,128,128,256] ----
__global__ LB void k_convt4m(const ushort* __restrict__ x3l, const ushort* __restrict__ wt,
                             const float* __restrict__ bias, ushort* __restrict__ xl) {
    int bx = blockIdx.x;
    int parity = bx & 3;
    int py = parity >> 1, px = parity & 1;
    int rg = (bx >> 2) & 15;
    int ct = (bx >> 6) & 3;
    int b  = bx >> 8;
    int co0 = ct * 64;
    int t = threadIdx.x;
    int w = t >> 6;
    int ip = rg * 4 + w;
    int lane = t & 63;
    int lanep = lane & 15;
    int hi = lane >> 4;
    int laneq = hi * 8;

    f32x4 acc[4][4];
    #pragma unroll
    for (int m = 0; m < 4; ++m)
        #pragma unroll
        for (int n = 0; n < 4; ++n) acc[m][n] = (f32x4){0.f, 0.f, 0.f, 0.f};

    #pragma unroll
    for (int ky = 0; ky < 3; ++ky) {
        if (((ky + py) & 1) == 0) continue;
        int i = ip + ((py == 1 && ky == 0) ? 1 : 0);
        if (i >= 64) continue;
        #pragma unroll
        for (int kx = 0; kx < 3; ++kx) {
            if (((kx + px) & 1) == 0) continue;
            int dxp = (px == 1 && kx == 0) ? 1 : 0;
            int tap = ky * 3 + kx;
            const ushort* wbase = wt + (((long)tap * 256 + co0 + lanep) << 7) + laneq;
            const ushort* xbase = x3l + ((((long)b << 12) + (i << 6)) << 7) + laneq;
            #pragma unroll
            for (int ci0 = 0; ci0 < 128; ci0 += 32) {
                frag16 av[4], bv[4];
                #pragma unroll
                for (int m = 0; m < 4; ++m)
                    av[m] = *(const frag16*)(wbase + ((m * 16) << 7) + ci0);
                #pragma unroll
                for (int n = 0; n < 4; ++n) {
                    int j = n * 16 + lanep + dxp;
                    bool valid = j < 64;
                    frag16 v = *(const frag16*)(xbase + ((valid ? j : 63) << 7) + ci0);
                    if (!valid) v = (frag16)(short)0;
                    bv[n] = v;
                }
                #pragma unroll
                for (int m = 0; m < 4; ++m)
                    #pragma unroll
                    for (int n = 0; n < 4; ++n)
                        acc[m][n] = __builtin_amdgcn_mfma_f32_16x16x32_bf16(av[m], bv[n], acc[m][n], 0, 0, 0);
            }
        }
    }

    float bvv[4][4];
    #pragma unroll
    for (int m = 0; m < 4; ++m)
        #pragma unroll
        for (int r = 0; r < 4; ++r)
            bvv[m][r] = bias[co0 + m * 16 + hi * 4 + r];
    int y = 2 * ip + py;
    #pragma unroll
    for (int n = 0; n < 4; ++n) {
        int x = 2 * (n * 16 + lanep) + px;
        long pb = ((((long)b << 14) + (y << 7) + x) << 8) + co0 + hi * 4;
        #pragma unroll
        for (int m = 0; m < 4; ++m) {
            ushort4 o;
            o.x = f2bf(acc[m][n][0] + bvv[m][0]);
            o.y = f2bf(acc[m][n][1] + bvv[m][1]);
            o.z = f2bf(acc[m][n][2] + bvv[m][2]);
            o.w = f2bf(acc[m][n][3] + bvv[m][3]);
            *(ushort4*)(xl + pb + m * 16) = o;
        }
    }
}

// ---------------- conv5 MFMA implicit GEMM v7: single-buffer global_load_lds (m97 recipe) ----
// xl: [8][128][128][256] bf16; wt: [9][512][256] bf16
// block (256 thr, 4 waves): b, co-tile 64 (ct 0..7), row-pair (yp 0..63).
// LDS single buffer: Xs@0 (33,280B) + Ws@16640 (36,864B) = 70,144B -> 2 blocks/CU.
// LDS written LINEARLY by global_load_lds; XOR bank-swizzle (q ^= (p>>1)&3, involution)
// applied on per-lane GLOBAL source addresses (rule #21); reads use the same swizzle.
__global__ void __launch_bounds__(256, 2)
k_conv5m(const ushort* __restrict__ xl, const ushort* __restrict__ wt,
         const float* __restrict__ bias, const int* __restrict__ lab,
         float* __restrict__ sumbuf) {
    __shared__ __align__(16) ushort L[35072];
    float* part = (float*)L;                 // aliased in epilogue (4,864 B)
    constexpr int XS = 0, WS = 16640;

    int bx = blockIdx.x;
    int yp = bx & 63;
    int ct = (bx >> 6) & 7;
    int b  = bx >> 9;
    int y0 = yp * 2, cob = ct * 64;
    int t = threadIdx.x;
    int w = t >> 6;
    int lane = t & 63;
    int row_w = w & 1;
    int col0 = (w >> 1) * 64;
    int lanep = lane & 15;
    int hi = lane >> 4;
    int xw8 = (hi ^ ((lanep >> 1) & 3)) * 8;   // W-read swizzle (lane-const)

    long xbase = (long)b << 14;
    long xg[9]; int wg[9];
    #pragma unroll
    for (int k = 0; k < 9; ++k) {
        int e = t + k * 256;
        int q = e & 3, p = e >> 2;
        int qp = q ^ ((p >> 1) & 3);
        if (e < 2080) {
            int r = p / 130, c = p - r * 130;
            int gy = reflect128(y0 - 1 + r);
            int gc = reflect128(c - 1);
            xg[k] = ((xbase + (gy << 7) + gc) << 8) + qp * 8;
        } else xg[k] = xbase << 8;             // never issued
        wg[k] = (((p >> 6) * 512 + cob + (p & 63)) << 8) + qp * 8;  // p = tap*64+co_l
    }

    f32x4 acc[4][4];
    #pragma unroll
    for (int m = 0; m < 4; ++m)
        #pragma unroll
        for (int n = 0; n < 4; ++n) acc[m][n] = (f32x4){0.f, 0.f, 0.f, 0.f};

    #pragma unroll 1
    for (int c8 = 0; c8 < 8; ++c8) {
        int cin = c8 * 32;
        #pragma unroll
        for (int k = 0; k < 8; ++k) gll16(xl + xg[k] + cin, L + XS + ((k << 8) + t) * 8);
        if (t < 32) gll16(xl + xg[8] + cin, L + XS + ((8 << 8) + t) * 8);
        #pragma unroll
        for (int k = 0; k < 9; ++k) gll16(wt + wg[k] + cin, L + WS + ((k << 8) + t) * 8);
        __syncthreads();   // drains vmcnt(0): staged data visible
        #pragma unroll
        for (int tap = 0; tap < 9; ++tap) {
            int ky = tap / 3, kx = tap % 3;
            frag16 av[4];
            #pragma unroll
            for (int m = 0; m < 4; ++m)
                av[m] = *(const frag16*)(L + WS + (tap * 64 + m * 16 + lanep) * 32 + xw8);
            int p0 = (row_w + ky) * 130 + col0 + kx + lanep;
            int bo = p0 * 32 + (hi ^ ((p0 >> 1) & 3)) * 8;
            frag16 bf[4];
            #pragma unroll
            for (int n = 0; n < 4; ++n)
                bf[n] = *(const frag16*)(L + XS + bo + n * 512);
            #pragma unroll
            for (int m = 0; m < 4; ++m)
                #pragma unroll
                for (int n = 0; n < 4; ++n)
                    acc[m][n] = __builtin_amdgcn_mfma_f32_16x16x32_bf16(av[m], bf[n], acc[m][n], 0, 0, 0);
        }
        __syncthreads();   // reads complete before next chunk overwrites
    }

    // ---- epilogue: bias + tanh + per-class partial sums (part aliases L) ----
    float bv[4][4];
    #pragma unroll
    for (int m = 0; m < 4; ++m)
        #pragma unroll
        for (int r = 0; r < 4; ++r)
            bv[m][r] = bias[cob + m * 16 + hi * 4 + r];

    for (int e = t; e < S * 64; e += 256) part[e] = 0.f;
    __syncthreads();

    int y = y0 + row_w;
    #pragma unroll
    for (int n = 0; n < 4; ++n) {
        int x = col0 + n * 16 + lanep;
        int s = lab[(b << 14) + (y << 7) + x];
        #pragma unroll
        for (int m = 0; m < 4; ++m)
            #pragma unroll
            for (int r = 0; r < 4; ++r)
                atomicAdd(&part[s * 64 + m * 16 + hi * 4 + r], tanhf(acc[m][n][r] + bv[m][r]));
    }
    __syncthreads();
    for (int e = t; e < S * 64; e += 256) {
        int s = e >> 6, col = e & 63;
        atomicAdd(&sumbuf[((b * S + s) << 9) + cob + col], part[e]);
    }
}

// ---------------- finalize ----------------
__global__ LB void k_final(const float* __restrict__ sumbuf, const int* __restrict__ counts,
                           float* __restrict__ out) {
    int idx = blockIdx.x * 256 + threadIdx.x;   // 8*19*512
    int tt = idx >> 9;
    int s = tt % S, b = tt / S;
    int cnt = counts[b * S + s];
    out[idx] = cnt > 0 ? sumbuf[idx] / (float)cnt : 0.f;
}

extern "C" void kernel_launch(void* const* d_in, const int* in_sizes, int n_in,
                              void* d_out, int out_size, void* d_ws, size_t ws_size,
                              hipStream_t stream) {
    const float* input  = (const float*)d_in[0];
    const float* segmap = (const float*)d_in[1];
    const float* w1 = (const float*)d_in[2];  const float* b1 = (const float*)d_in[3];
    const float* w2 = (const float*)d_in[4];  const float* b2 = (const float*)d_in[5];
    const float* w3 = (const float*)d_in[6];  const float* b3 = (const float*)d_in[7];
    const float* w4 = (const float*)d_in[8];  const float* b4 = (const float*)d_in[9];
    const float* w5 = (const float*)d_in[10]; const float* b5 = (const float*)d_in[11];
    float* out = (float*)d_out;

    float* ws = (float*)d_ws;
    ushort* xl    = (ushort*)ws;                  // [8,128,128,256] bf16
    ushort* x1l   = (ushort*)(ws + 16777216);     // [8,256,256,32]
    ushort* x2l   = (ushort*)(ws + 25165824);     // [8,128,128,64]
    ushort* x3l   = (ushort*)(ws + 29360128);     // [8,64,64,128]
    int*   lab    = (int*)(ws + 31539200);        // 131,072
    ushort* wt5   = (ushort*)(ws + 31670528);     // 1,179,648 bf16
    ushort* wt4t  = (ushort*)(ws + 32260352);     // 294,912 bf16
    ushort* wt2   = (ushort*)(ws + 32407808);     // 18,432 bf16
    ushort* wt3   = (ushort*)(ws + 32417024);     // 73,728 bf16
    // zero region (contiguous, cleared by k_prep): sumbuf, counts, stat accumulators
    float* zbase  = ws + 32453888;
    float* sumbuf = zbase;                        // 77,824
    int*   counts = (int*)(zbase + 77824);        // 256
    float* ps1    = zbase + 78080;                // 256
    float* qs1    = zbase + 78336;                // 256
    float* ps2    = zbase + 78592;                // 512
    float* qs2    = zbase + 79104;                // 512
    float* ps3    = zbase + 79616;                // 1,024
    float* qs3    = zbase + 80640;                // 1,024
    float* ps4    = zbase + 81664;                // 2,048
    float* qs4    = zbase + 83712;                // 2,048
    const int ZN  = 85760;

    // prep: weight transposes + zero all accumulators
    k_prep<<<6120, 256, 0, stream>>>(w2, w3, w4, w5, wt2, wt3, wt4t, wt5, zbase, ZN);
    // layer 1 (+ fused label map; counts zeroed by k_prep above)
    k_conv1cl<<<2048, 256, 0, stream>>>(input, w1, b1, x1l, segmap, lab, counts);
    k_stats_cl<32, 1024, 64><<<512, 256, 0, stream>>>(x1l, ps1, qs1);
    k_nl_cl<32, 65536><<<8192, 256, 0, stream>>>(x1l, ps1, qs1);
    // layer 2
    k_conv2m<<<1024, 256, 0, stream>>>(x1l, wt2, b2, x2l);
    k_stats_cl<64, 512, 32><<<256, 256, 0, stream>>>(x2l, ps2, qs2);
    k_nl_cl<64, 16384><<<4096, 256, 0, stream>>>(x2l, ps2, qs2);
    // layer 3
    k_conv3m<<<512, 256, 0, stream>>>(x2l, wt3, b3, x3l);
    k_stats_cl<128, 256, 16><<<128, 256, 0, stream>>>(x3l, ps3, qs3);
    k_nl_cl<128, 4096><<<2048, 256, 0, stream>>>(x3l, ps3, qs3);
    // layer 4 (transpose conv)
    k_convt4m<<<2048, 256, 0, stream>>>(x3l, wt4t, b4, xl);
    k_stats_cl<256, 512, 32><<<256, 256, 0, stream>>>(xl, ps4, qs4);
    k_nl_cl<256, 16384><<<16384, 256, 0, stream>>>(xl, ps4, qs4);
    // layer 5: MFMA implicit GEMM v7 (single-buffer gload_lds) + masked class-sum
    k_conv5m<<<4096, 256, 0, stream>>>(xl, wt5, b5, lab, sumbuf);
    // finalize
    k_final<<<304, 256, 0, stream>>>(sumbuf, counts, out);
}